// Round 1
// baseline (3970.864 us; speedup 1.0000x reference)
//
#include <hip/hip_runtime.h>

// NeuralODE RK4: 10 steps x 4 stages x 3 GEMMs (8192x1024x1024), bf16 MFMA,
// fused epilogues (tanh / RK4 combine). fp32 h state; bf16 activations.

typedef __attribute__((ext_vector_type(8))) __bf16 bf16x8;
typedef __attribute__((ext_vector_type(4))) float f32x4;
typedef unsigned short ushort_t;

#define GLOAD16(gp, lp) \
  __builtin_amdgcn_global_load_lds((const __attribute__((address_space(1))) unsigned int*)(gp), \
                                   (__attribute__((address_space(3))) unsigned int*)(lp), 16, 0, 0)

__device__ __forceinline__ ushort_t f2bf(float f) {
  union { float f; unsigned u; } v; v.f = f;
  unsigned r = v.u + 0x7fffu + ((v.u >> 16) & 1u);   // RNE
  return (ushort_t)(r >> 16);
}

__device__ __forceinline__ float fast_tanh(float x) {
  // tanh(x) = 1 - 2/(e^{2x}+1); handles +-inf saturation correctly.
  float e = __expf(2.0f * x);
  return 1.0f - 2.0f * __builtin_amdgcn_rcpf(e + 1.0f);
}

// ---------------- weight transpose (K x N fp32 -> N x K bf16) ----------------
__global__ void transpose_bf16(const float* __restrict__ in, ushort_t* __restrict__ out) {
  __shared__ float tile[32][33];
  const int bx = blockIdx.x * 32, by = blockIdx.y * 32;
  const int tx = threadIdx.x, ty = threadIdx.y;
#pragma unroll
  for (int i = 0; i < 32; i += 8)
    tile[ty + i][tx] = in[(size_t)(by + ty + i) * 1024 + bx + tx];
  __syncthreads();
#pragma unroll
  for (int i = 0; i < 32; i += 8)
    out[(size_t)(bx + ty + i) * 1024 + by + tx] = f2bf(tile[tx][ty + i]);
}

// ---------------- fp32 -> bf16 convert (initial h) ----------------
__global__ void conv_bf16(const float* __restrict__ in, ushort_t* __restrict__ out) {
  size_t i = ((size_t)blockIdx.x * 256 + threadIdx.x) * 4;
  float4 v = *(const float4*)&in[i];
  ushort4 o;
  o.x = f2bf(v.x); o.y = f2bf(v.y); o.z = f2bf(v.z); o.w = f2bf(v.w);
  *(ushort4*)&out[i] = o;
}

// ---------------- fused GEMM ----------------
// C[MxN] = A[MxK] * Bt[NxK]^T   (A bf16 row-major, Bt bf16 row-major N x K)
// MODE 1: Xout = bf16(tanh(C + bias + tval*wlast))
// MODE 2: Xout = bf16(tanh(C + bias))
// MODE 3: k = C + bias; RK4 stage S:
//   S0: h1 = h0 + dt/6*k;  Xout = bf16(h0 + dt/2*k)
//   S1: h1 += dt/3*k;      Xout = bf16(h0 + dt/2*k)
//   S2: h1 += dt/3*k;      Xout = bf16(h0 + dt*k)
//   S3: h1 += dt/6*k;      Xout = bf16(h1)
template<int MODE, int S>
__global__ void __launch_bounds__(256)
gemm_fused(const ushort_t* __restrict__ Ag, const ushort_t* __restrict__ Bg,
           const float* __restrict__ bias, const float* __restrict__ wlast, float tval,
           ushort_t* __restrict__ Xout,
           const float* __restrict__ h0, float* __restrict__ h1)
{
  constexpr int K = 1024, N = 1024, BK = 32;
  constexpr float DT = 0.1f;
  __shared__ ushort_t ldsA[2][128 * 32];
  __shared__ ushort_t ldsB[2][128 * 32];

  // XCD-aware swizzle: 512 blocks, 8 XCDs -> XCD x owns bm in [8x, 8x+8)
  const int bid = blockIdx.x;
  const int logical = (bid & 7) * 64 + (bid >> 3);
  const int bm0 = (logical >> 3) * 128;
  const int bn0 = (logical & 7) * 128;

  const int tid = threadIdx.x;
  const int w = tid >> 6, l = tid & 63;
  const int wr = w >> 1, wc = w & 1;

  const int srow = l >> 2;          // row within 16-row chunk
  const int scol = (l & 3) * 8;     // col (elements)

  f32x4 acc[4][4];
#pragma unroll
  for (int m = 0; m < 4; ++m)
#pragma unroll
    for (int n = 0; n < 4; ++n) acc[m][n] = (f32x4){0.f, 0.f, 0.f, 0.f};

  const ushort_t* Abase = Ag + (size_t)bm0 * K;
  const ushort_t* Bbase = Bg + (size_t)bn0 * K;

#define STAGE_TILE(buf, k0) do { \
    GLOAD16(Abase + (size_t)(w * 16 + srow) * K + (k0) + scol,       &ldsA[buf][w * 512]); \
    GLOAD16(Abase + (size_t)((w + 4) * 16 + srow) * K + (k0) + scol, &ldsA[buf][(w + 4) * 512]); \
    GLOAD16(Bbase + (size_t)(w * 16 + srow) * K + (k0) + scol,       &ldsB[buf][w * 512]); \
    GLOAD16(Bbase + (size_t)((w + 4) * 16 + srow) * K + (k0) + scol, &ldsB[buf][(w + 4) * 512]); \
  } while (0)

  STAGE_TILE(0, 0);

  const int r = l & 15, kb = l >> 4;
  constexpr int NT = K / BK;  // 32

#pragma unroll 2
  for (int t = 0; t < NT; ++t) {
    __syncthreads();                 // drains vmcnt -> staged tile ready; joins waves
    const int buf = t & 1;
    if (t + 1 < NT) STAGE_TILE(buf ^ 1, (t + 1) * BK);
    bf16x8 af[4], bfr[4];
#pragma unroll
    for (int m = 0; m < 4; ++m)
      af[m] = *(const bf16x8*)&ldsA[buf][(wr * 64 + m * 16 + r) * 32 + kb * 8];
#pragma unroll
    for (int n = 0; n < 4; ++n)
      bfr[n] = *(const bf16x8*)&ldsB[buf][(wc * 64 + n * 16 + r) * 32 + kb * 8];
#pragma unroll
    for (int m = 0; m < 4; ++m)
#pragma unroll
      for (int n = 0; n < 4; ++n)
        acc[m][n] = __builtin_amdgcn_mfma_f32_16x16x32_bf16(af[m], bfr[n], acc[m][n], 0, 0, 0);
  }
#undef STAGE_TILE

  // epilogue: C/D layout col = lane&15, row = (lane>>4)*4 + reg
  const int er = (l >> 4) * 4;
  const int ec = l & 15;
#pragma unroll
  for (int n = 0; n < 4; ++n) {
    const int gcol = bn0 + wc * 64 + n * 16 + ec;
    const float bv = bias[gcol];
    const float wl = (MODE == 1) ? wlast[gcol] : 0.f;
#pragma unroll
    for (int m = 0; m < 4; ++m) {
#pragma unroll
      for (int j = 0; j < 4; ++j) {
        const int grow = bm0 + wr * 64 + m * 16 + er + j;
        const size_t idx = (size_t)grow * N + gcol;
        const float v = acc[m][n][j];
        if (MODE == 1) {
          Xout[idx] = f2bf(fast_tanh(v + bv + tval * wl));
        } else if (MODE == 2) {
          Xout[idx] = f2bf(fast_tanh(v + bv));
        } else {
          const float k = v + bv;
          if (S == 0) {
            const float h0v = h0[idx];
            h1[idx] = h0v + (DT / 6.f) * k;
            Xout[idx] = f2bf(h0v + (DT * 0.5f) * k);
          } else if (S == 1) {
            const float h0v = h0[idx];
            h1[idx] += (DT / 3.f) * k;
            Xout[idx] = f2bf(h0v + (DT * 0.5f) * k);
          } else if (S == 2) {
            const float h0v = h0[idx];
            h1[idx] += (DT / 3.f) * k;
            Xout[idx] = f2bf(h0v + DT * k);
          } else {
            const float hn = h1[idx] + (DT / 6.f) * k;
            h1[idx] = hn;
            Xout[idx] = f2bf(hn);
          }
        }
      }
    }
  }
}

extern "C" void kernel_launch(void* const* d_in, const int* in_sizes, int n_in,
                              void* d_out, int out_size, void* d_ws, size_t ws_size,
                              hipStream_t stream) {
  (void)in_sizes; (void)n_in; (void)out_size; (void)ws_size;
  const float* h_in = (const float*)d_in[0];
  const float* W1   = (const float*)d_in[1];   // 1025 x 1024
  const float* b1   = (const float*)d_in[2];
  const float* W2   = (const float*)d_in[3];   // 1024 x 1024
  const float* b2   = (const float*)d_in[4];
  const float* W3   = (const float*)d_in[5];
  const float* b3   = (const float*)d_in[6];

  char* ws = (char*)d_ws;
  ushort_t* W1t  = (ushort_t*)(ws);                        // 2 MiB
  ushort_t* W2t  = (ushort_t*)(ws + (2ull << 20));         // 2 MiB
  ushort_t* W3t  = (ushort_t*)(ws + (4ull << 20));         // 2 MiB
  ushort_t* hinb = (ushort_t*)(ws + (6ull << 20));         // 16 MiB
  ushort_t* X1   = (ushort_t*)(ws + (22ull << 20));        // 16 MiB
  ushort_t* X2   = (ushort_t*)(ws + (38ull << 20));        // 16 MiB
  float*    B0   = (float*)(ws + (54ull << 20));           // 32 MiB
  float*    OUT  = (float*)d_out;

  dim3 tb(32, 8);
  dim3 tg(32, 32);
  transpose_bf16<<<tg, tb, 0, stream>>>(W1, W1t);   // first 1024 rows of W1
  transpose_bf16<<<tg, tb, 0, stream>>>(W2, W2t);
  transpose_bf16<<<tg, tb, 0, stream>>>(W3, W3t);
  conv_bf16<<<8192, 256, 0, stream>>>(h_in, hinb);

  const float dt = 0.1f;
  const float* W1last = W1 + (size_t)1024 * 1024;
  const float* hcur = h_in;

  for (int step = 0; step < 10; ++step) {
    const float t0 = step * dt;
    float* hnext = (step & 1) ? OUT : B0;

    // stage 0 (t = t0)
    gemm_fused<1, 0><<<512, 256, 0, stream>>>(hinb, W1t, b1, W1last, t0, X1, nullptr, nullptr);
    gemm_fused<2, 0><<<512, 256, 0, stream>>>(X1, W2t, b2, nullptr, 0.f, X2, nullptr, nullptr);
    gemm_fused<3, 0><<<512, 256, 0, stream>>>(X2, W3t, b3, nullptr, 0.f, hinb, hcur, hnext);

    // stage 1 (t = t0 + dt/2)
    gemm_fused<1, 0><<<512, 256, 0, stream>>>(hinb, W1t, b1, W1last, t0 + 0.5f * dt, X1, nullptr, nullptr);
    gemm_fused<2, 0><<<512, 256, 0, stream>>>(X1, W2t, b2, nullptr, 0.f, X2, nullptr, nullptr);
    gemm_fused<3, 1><<<512, 256, 0, stream>>>(X2, W3t, b3, nullptr, 0.f, hinb, hcur, hnext);

    // stage 2 (t = t0 + dt/2)
    gemm_fused<1, 0><<<512, 256, 0, stream>>>(hinb, W1t, b1, W1last, t0 + 0.5f * dt, X1, nullptr, nullptr);
    gemm_fused<2, 0><<<512, 256, 0, stream>>>(X1, W2t, b2, nullptr, 0.f, X2, nullptr, nullptr);
    gemm_fused<3, 2><<<512, 256, 0, stream>>>(X2, W3t, b3, nullptr, 0.f, hinb, hcur, hnext);

    // stage 3 (t = t0 + dt)
    gemm_fused<1, 0><<<512, 256, 0, stream>>>(hinb, W1t, b1, W1last, t0 + dt, X1, nullptr, nullptr);
    gemm_fused<2, 0><<<512, 256, 0, stream>>>(X1, W2t, b2, nullptr, 0.f, X2, nullptr, nullptr);
    gemm_fused<3, 3><<<512, 256, 0, stream>>>(X2, W3t, b3, nullptr, 0.f, hinb, hcur, hnext);

    hcur = hnext;
  }
}

// Round 2
// 2957.035 us; speedup vs baseline: 1.3429x; 1.3429x over previous
//
#include <hip/hip_runtime.h>

// NeuralODE RK4: 10 steps x 4 stages x 3 GEMMs (8192x1024x1024), bf16 MFMA.
// GEMM: 256x128 tile, BK=64, 8 waves (64x64 each), triple-buffered LDS,
// counted vmcnt(6) pipeline, XOR-swizzled LDS (pre-swizzled global source),
// raw s_barrier, setprio around MFMA. Fused epilogues; bf16 ksum RK4 state.

typedef __attribute__((ext_vector_type(8))) __bf16 bf16x8;
typedef __attribute__((ext_vector_type(4))) float f32x4;
typedef unsigned short ushort_t;

#define GLOAD16(gp, lp) \
  __builtin_amdgcn_global_load_lds((const __attribute__((address_space(1))) unsigned int*)(gp), \
                                   (__attribute__((address_space(3))) unsigned int*)(lp), 16, 0, 0)

__device__ __forceinline__ ushort_t f2bf(float f) {
  union { float f; unsigned u; } v; v.f = f;
  unsigned r = v.u + 0x7fffu + ((v.u >> 16) & 1u);   // RNE
  return (ushort_t)(r >> 16);
}
__device__ __forceinline__ float b2f(ushort_t u) {
  union { unsigned u; float f; } v; v.u = ((unsigned)u) << 16; return v.f;
}
__device__ __forceinline__ float fast_tanh(float x) {
  float e = __expf(2.0f * x);
  return 1.0f - 2.0f * __builtin_amdgcn_rcpf(e + 1.0f);
}

// ---------------- weight transpose (K x N fp32 -> N x K bf16) ----------------
__global__ void transpose_bf16(const float* __restrict__ in, ushort_t* __restrict__ out) {
  __shared__ float tile[32][33];
  const int bx = blockIdx.x * 32, by = blockIdx.y * 32;
  const int tx = threadIdx.x, ty = threadIdx.y;
#pragma unroll
  for (int i = 0; i < 32; i += 8)
    tile[ty + i][tx] = in[(size_t)(by + ty + i) * 1024 + bx + tx];
  __syncthreads();
#pragma unroll
  for (int i = 0; i < 32; i += 8)
    out[(size_t)(bx + ty + i) * 1024 + by + tx] = f2bf(tile[tx][ty + i]);
}

// ---------------- fp32 -> bf16 convert (initial h -> hb) ----------------
__global__ void conv_bf16(const float* __restrict__ in, ushort_t* __restrict__ out) {
  size_t i = ((size_t)blockIdx.x * 256 + threadIdx.x) * 4;
  float4 v = *(const float4*)&in[i];
  ushort4 o;
  o.x = f2bf(v.x); o.y = f2bf(v.y); o.z = f2bf(v.z); o.w = f2bf(v.w);
  *(ushort4*)&out[i] = o;
}

// ---------------- fused GEMM ----------------
// C[MxN] = A[MxK] * Bt[NxK]^T, A/Bt bf16 row-major. M=8192, N=1024 grid-sliced.
// MODE 1: Xout = bf16(tanh(C + bias + tval*wlast))
// MODE 2: Xout = bf16(tanh(C + bias))
// MODE 3: kv = C + bias; RK4 stage S (dt=0.1):
//   S0: ksum = bf(kv);        Xout = bf(hb + dt/2*kv)
//   S1: ksum += 2kv;          Xout = bf(hb + dt/2*kv)
//   S2: ksum += 2kv;          Xout = bf(hb + dt*kv)
//   S3: hn = h0 + dt/6*(ksum + kv); h1 = hn; Xout(=hb) = bf(hn)
template<int MODE, int S>
__global__ void __launch_bounds__(512, 1)
gemm_fused(const ushort_t* __restrict__ Ag, const ushort_t* __restrict__ Bg,
           const float* __restrict__ bias, const float* __restrict__ wlast, float tval,
           ushort_t* __restrict__ Xout, ushort_t* __restrict__ ksum,
           const ushort_t* __restrict__ hbr,
           const float* __restrict__ h0, float* __restrict__ h1)
{
  constexpr int K = 1024, N = 1024, NT = 16;  // BK=64
  constexpr float DT = 0.1f;
  // per buffer: A 256x64 bf16 = 16384 elems, B 128x64 = 8192 elems
  __shared__ __align__(16) ushort_t ldsbuf[3][24576];

  // 256 blocks = 32 bm x 8 bn. XCD swizzle: xcd = bid&7 owns 32 consecutive
  // logical ids -> 4 A-panels (2MB) + full B (2MB) resident per XCD L2.
  const int bid = blockIdx.x;
  const int logical = (bid & 7) * 32 + (bid >> 3);
  const int bm0 = (logical >> 3) * 256;
  const int bn0 = (logical & 7) * 128;

  const int tid = threadIdx.x;
  const int w = tid >> 6, l = tid & 63;
  const int wr = w >> 1, wc = w & 1;          // 4M x 2N waves -> 64x64 per wave

  // ---- staging addressing (pre-swizzled global source, linear LDS dest) ----
  const int lr = l >> 3;                      // row within 8-row chunk-block
  const int clog = (l & 7) ^ lr;              // logical 16B-chunk index
  const size_t gAoff0 = (size_t)(bm0 + w * 32 + lr) * K + clog * 8;
  const size_t gBoff0 = (size_t)(bn0 + w * 16 + lr) * K + clog * 8;
  const int lAoff = w * 2048 + l * 8;         // elems; +512 per instr
  const int lBoff = 16384 + w * 1024 + l * 8;

#define STAGE_A01(s, t2) do { \
    const ushort_t* g = Ag + gAoff0 + (size_t)(t2) * 64; \
    GLOAD16(g,          &ldsbuf[s][lAoff]); \
    GLOAD16(g + 8 * K,  &ldsbuf[s][lAoff + 512]); } while (0)
#define STAGE_A23(s, t2) do { \
    const ushort_t* g = Ag + gAoff0 + (size_t)(t2) * 64; \
    GLOAD16(g + 16 * K, &ldsbuf[s][lAoff + 1024]); \
    GLOAD16(g + 24 * K, &ldsbuf[s][lAoff + 1536]); } while (0)
#define STAGE_B0(s, t2) do { \
    const ushort_t* g = Bg + gBoff0 + (size_t)(t2) * 64; \
    GLOAD16(g,          &ldsbuf[s][lBoff]); } while (0)
#define STAGE_B1(s, t2) do { \
    const ushort_t* g = Bg + gBoff0 + (size_t)(t2) * 64; \
    GLOAD16(g + 8 * K,  &ldsbuf[s][lBoff + 512]); } while (0)

  // ---- fragment read addressing (swizzled) ----
  const int r = l & 15, kb = l >> 4, xr = r & 7;
  const int aBase = (wr * 64 + r) * 64;       // + m*1024 + chunk*8
  const int bBase = 16384 + (wc * 64 + r) * 64;
  const int cOff0 = (kb ^ xr) * 8;            // ks=0 chunk
  const int cOff1 = ((4 | kb) ^ xr) * 8;      // ks=1 chunk

  f32x4 acc[4][4];
#pragma unroll
  for (int m = 0; m < 4; ++m)
#pragma unroll
    for (int n = 0; n < 4; ++n) acc[m][n] = (f32x4){0.f, 0.f, 0.f, 0.f};

  // prologue: stage tiles 0, 1
  STAGE_A01(0, 0); STAGE_A23(0, 0); STAGE_B0(0, 0); STAGE_B1(0, 0);
  STAGE_A01(1, 1); STAGE_A23(1, 1); STAGE_B0(1, 1); STAGE_B1(1, 1);

  int cur = 0;
  for (int t = 0; t < NT; ++t) {
    int s2 = cur + 2; if (s2 >= 3) s2 -= 3;
    // tile t resident after my 6 oldest loads retire; tile t+1 stays in flight
    if (t + 1 < NT) { asm volatile("s_waitcnt vmcnt(6)" ::: "memory"); }
    else            { asm volatile("s_waitcnt vmcnt(0)" ::: "memory"); }
    __builtin_amdgcn_s_barrier();
    __builtin_amdgcn_sched_barrier(0);

    const ushort_t* Lb = &ldsbuf[cur][0];
    bf16x8 av[4], bv[4];
    // ---- phase 0 (k-slice 0) ----
#pragma unroll
    for (int m = 0; m < 4; ++m) av[m] = *(const bf16x8*)(Lb + aBase + m * 1024 + cOff0);
#pragma unroll
    for (int n = 0; n < 4; ++n) bv[n] = *(const bf16x8*)(Lb + bBase + n * 1024 + cOff0);
    if (t + 2 < NT) { STAGE_A01(s2, t + 2); STAGE_B0(s2, t + 2); }
    __builtin_amdgcn_s_setprio(1);
#pragma unroll
    for (int m = 0; m < 4; ++m)
#pragma unroll
      for (int n = 0; n < 4; ++n)
        acc[m][n] = __builtin_amdgcn_mfma_f32_16x16x32_bf16(av[m], bv[n], acc[m][n], 0, 0, 0);
    __builtin_amdgcn_s_setprio(0);
    __builtin_amdgcn_s_barrier();
    // ---- phase 1 (k-slice 1) ----
#pragma unroll
    for (int m = 0; m < 4; ++m) av[m] = *(const bf16x8*)(Lb + aBase + m * 1024 + cOff1);
#pragma unroll
    for (int n = 0; n < 4; ++n) bv[n] = *(const bf16x8*)(Lb + bBase + n * 1024 + cOff1);
    if (t + 2 < NT) { STAGE_A23(s2, t + 2); STAGE_B1(s2, t + 2); }
    __builtin_amdgcn_s_setprio(1);
#pragma unroll
    for (int m = 0; m < 4; ++m)
#pragma unroll
      for (int n = 0; n < 4; ++n)
        acc[m][n] = __builtin_amdgcn_mfma_f32_16x16x32_bf16(av[m], bv[n], acc[m][n], 0, 0, 0);
    __builtin_amdgcn_s_setprio(0);

    ++cur; if (cur == 3) cur = 0;
  }
#undef STAGE_A01
#undef STAGE_A23
#undef STAGE_B0
#undef STAGE_B1

  // epilogue: C/D layout col = lane&15, row = (lane>>4)*4 + reg
  const int er = (l >> 4) * 4;
  const int ec = l & 15;
#pragma unroll
  for (int n = 0; n < 4; ++n) {
    const int gcol = bn0 + wc * 64 + n * 16 + ec;
    const float bvx = bias[gcol];
    const float wl = (MODE == 1) ? wlast[gcol] : 0.f;
#pragma unroll
    for (int m = 0; m < 4; ++m) {
#pragma unroll
      for (int j = 0; j < 4; ++j) {
        const int grow = bm0 + wr * 64 + m * 16 + er + j;
        const size_t idx = (size_t)grow * N + gcol;
        const float v = acc[m][n][j];
        if (MODE == 1) {
          Xout[idx] = f2bf(fast_tanh(v + bvx + tval * wl));
        } else if (MODE == 2) {
          Xout[idx] = f2bf(fast_tanh(v + bvx));
        } else {
          const float kv = v + bvx;
          if (S == 0) {
            ksum[idx] = f2bf(kv);
            Xout[idx] = f2bf(b2f(hbr[idx]) + (DT * 0.5f) * kv);
          } else if (S == 1) {
            ksum[idx] = f2bf(b2f(ksum[idx]) + 2.f * kv);
            Xout[idx] = f2bf(b2f(hbr[idx]) + (DT * 0.5f) * kv);
          } else if (S == 2) {
            ksum[idx] = f2bf(b2f(ksum[idx]) + 2.f * kv);
            Xout[idx] = f2bf(b2f(hbr[idx]) + DT * kv);
          } else {
            const float hn = h0[idx] + (DT / 6.f) * (b2f(ksum[idx]) + kv);
            h1[idx] = hn;
            Xout[idx] = f2bf(hn);   // Xout == hb (next step's stage-0 input)
          }
        }
      }
    }
  }
}

extern "C" void kernel_launch(void* const* d_in, const int* in_sizes, int n_in,
                              void* d_out, int out_size, void* d_ws, size_t ws_size,
                              hipStream_t stream) {
  (void)in_sizes; (void)n_in; (void)out_size; (void)ws_size;
  const float* h_in = (const float*)d_in[0];
  const float* W1   = (const float*)d_in[1];   // 1025 x 1024
  const float* b1   = (const float*)d_in[2];
  const float* W2   = (const float*)d_in[3];
  const float* b2   = (const float*)d_in[4];
  const float* W3   = (const float*)d_in[5];
  const float* b3   = (const float*)d_in[6];

  char* ws = (char*)d_ws;
  ushort_t* W1t  = (ushort_t*)(ws);                        // 2 MiB
  ushort_t* W2t  = (ushort_t*)(ws + (2ull << 20));         // 2 MiB
  ushort_t* W3t  = (ushort_t*)(ws + (4ull << 20));         // 2 MiB
  ushort_t* hb   = (ushort_t*)(ws + (6ull << 20));         // 16 MiB bf16 h
  ushort_t* X1   = (ushort_t*)(ws + (22ull << 20));        // 16 MiB
  ushort_t* X2   = (ushort_t*)(ws + (38ull << 20));        // 16 MiB
  ushort_t* Xs   = (ushort_t*)(ws + (54ull << 20));        // 16 MiB stage input
  ushort_t* KS   = (ushort_t*)(ws + (70ull << 20));        // 16 MiB bf16 ksum
  float*    OUT  = (float*)d_out;                          // fp32 h (in-place)

  dim3 tb(32, 8);
  dim3 tg(32, 32);
  transpose_bf16<<<tg, tb, 0, stream>>>(W1, W1t);
  transpose_bf16<<<tg, tb, 0, stream>>>(W2, W2t);
  transpose_bf16<<<tg, tb, 0, stream>>>(W3, W3t);
  conv_bf16<<<8192, 256, 0, stream>>>(h_in, hb);

  const float dt = 0.1f;
  const float* W1last = W1 + (size_t)1024 * 1024;
  constexpr int GRID = 256, BLK = 512;

  for (int step = 0; step < 10; ++step) {
    const float t0 = step * dt;
    const float* h0p = (step == 0) ? h_in : (const float*)OUT;

    // stage 0 (t = t0), A = hb
    gemm_fused<1, 0><<<GRID, BLK, 0, stream>>>(hb, W1t, b1, W1last, t0, X1, nullptr, nullptr, nullptr, nullptr);
    gemm_fused<2, 0><<<GRID, BLK, 0, stream>>>(X1, W2t, b2, nullptr, 0.f, X2, nullptr, nullptr, nullptr, nullptr);
    gemm_fused<3, 0><<<GRID, BLK, 0, stream>>>(X2, W3t, b3, nullptr, 0.f, Xs, KS, hb, nullptr, nullptr);

    // stage 1 (t = t0 + dt/2), A = Xs
    gemm_fused<1, 0><<<GRID, BLK, 0, stream>>>(Xs, W1t, b1, W1last, t0 + 0.5f * dt, X1, nullptr, nullptr, nullptr, nullptr);
    gemm_fused<2, 0><<<GRID, BLK, 0, stream>>>(X1, W2t, b2, nullptr, 0.f, X2, nullptr, nullptr, nullptr, nullptr);
    gemm_fused<3, 1><<<GRID, BLK, 0, stream>>>(X2, W3t, b3, nullptr, 0.f, Xs, KS, hb, nullptr, nullptr);

    // stage 2 (t = t0 + dt/2)
    gemm_fused<1, 0><<<GRID, BLK, 0, stream>>>(Xs, W1t, b1, W1last, t0 + 0.5f * dt, X1, nullptr, nullptr, nullptr, nullptr);
    gemm_fused<2, 0><<<GRID, BLK, 0, stream>>>(X1, W2t, b2, nullptr, 0.f, X2, nullptr, nullptr, nullptr, nullptr);
    gemm_fused<3, 2><<<GRID, BLK, 0, stream>>>(X2, W3t, b3, nullptr, 0.f, Xs, KS, hb, nullptr, nullptr);

    // stage 3 (t = t0 + dt); S3 writes h1 (in-place OUT) + hb
    gemm_fused<1, 0><<<GRID, BLK, 0, stream>>>(Xs, W1t, b1, W1last, t0 + dt, X1, nullptr, nullptr, nullptr, nullptr);
    gemm_fused<2, 0><<<GRID, BLK, 0, stream>>>(X1, W2t, b2, nullptr, 0.f, X2, nullptr, nullptr, nullptr, nullptr);
    gemm_fused<3, 3><<<GRID, BLK, 0, stream>>>(X2, W3t, b3, nullptr, 0.f, hb, KS, nullptr, h0p, OUT);
  }
}

// Round 3
// 2849.726 us; speedup vs baseline: 1.3934x; 1.0377x over previous
//
#include <hip/hip_runtime.h>

// NeuralODE RK4: 10 steps x 4 stages x 3 GEMMs (8192x1024x1024), bf16 MFMA.
// GEMM: 128x128 tile, BK=64, 4 waves (64x64 each), 2 LDS buffers (64KB ->
// 2 blocks/CU for latency hiding), counted vmcnt(8), XOR-swizzled LDS
// (pre-swizzled global source), raw s_barrier, setprio, LDS-staged
// vectorized epilogue (16B coalesced stores). bf16 ksum RK4 state.

typedef __attribute__((ext_vector_type(8))) __bf16 bf16x8;
typedef __attribute__((ext_vector_type(4))) float f32x4;
typedef __attribute__((ext_vector_type(8))) float f32x8;
typedef __attribute__((ext_vector_type(8))) unsigned short us8;
typedef unsigned short ushort_t;

#define GLOAD16(gp, lp) \
  __builtin_amdgcn_global_load_lds((const __attribute__((address_space(1))) unsigned int*)(gp), \
                                   (__attribute__((address_space(3))) unsigned int*)(lp), 16, 0, 0)

__device__ __forceinline__ ushort_t f2bf(float f) {
  union { float f; unsigned u; } v; v.f = f;
  unsigned r = v.u + 0x7fffu + ((v.u >> 16) & 1u);   // RNE
  return (ushort_t)(r >> 16);
}
__device__ __forceinline__ float b2f(ushort_t u) {
  union { unsigned u; float f; } v; v.u = ((unsigned)u) << 16; return v.f;
}
__device__ __forceinline__ float fast_tanh(float x) {
  float e = __expf(2.0f * x);
  return 1.0f - 2.0f * __builtin_amdgcn_rcpf(e + 1.0f);
}

// ---------------- weight transpose (K x N fp32 -> N x K bf16) ----------------
__global__ void transpose_bf16(const float* __restrict__ in, ushort_t* __restrict__ out) {
  __shared__ float tile[32][33];
  const int bx = blockIdx.x * 32, by = blockIdx.y * 32;
  const int tx = threadIdx.x, ty = threadIdx.y;
#pragma unroll
  for (int i = 0; i < 32; i += 8)
    tile[ty + i][tx] = in[(size_t)(by + ty + i) * 1024 + bx + tx];
  __syncthreads();
#pragma unroll
  for (int i = 0; i < 32; i += 8)
    out[(size_t)(bx + ty + i) * 1024 + by + tx] = f2bf(tile[tx][ty + i]);
}

// ---------------- fp32 -> bf16 convert (initial h -> hb) ----------------
__global__ void conv_bf16(const float* __restrict__ in, ushort_t* __restrict__ out) {
  size_t i = ((size_t)blockIdx.x * 256 + threadIdx.x) * 4;
  float4 v = *(const float4*)&in[i];
  ushort4 o;
  o.x = f2bf(v.x); o.y = f2bf(v.y); o.z = f2bf(v.z); o.w = f2bf(v.w);
  *(ushort4*)&out[i] = o;
}

// ---------------- fused GEMM ----------------
// C[MxN] = A[MxK] * Bt[NxK]^T, A/Bt bf16 row-major. M=8192, N=K=1024.
// MODE 1: Xout = bf16(tanh(C + bias + tval*wlast))
// MODE 2: Xout = bf16(tanh(C + bias))
// MODE 3: kv = bf16(C + bias); RK4 stage S (dt=0.1):
//   S0: ksum = kv;            Xout = bf(hb + dt/2*kv)
//   S1: ksum += 2kv;          Xout = bf(hb + dt/2*kv)
//   S2: ksum += 2kv;          Xout = bf(hb + dt*kv)
//   S3: hn = h0 + dt/6*(ksum + kv); h1 = hn; Xout(=hb) = bf(hn)
template<int MODE, int S>
__global__ void __launch_bounds__(256, 2)
gemm_fused(const ushort_t* __restrict__ Ag, const ushort_t* __restrict__ Bg,
           const float* __restrict__ bias, const float* __restrict__ wlast, float tval,
           ushort_t* __restrict__ Xout, ushort_t* __restrict__ ksum,
           const ushort_t* __restrict__ hbr,
           const float* __restrict__ h0, float* __restrict__ h1)
{
  constexpr int K = 1024, NCOL = 1024, NT = 16;  // BK=64
  constexpr float DT = 0.1f;
  // per buffer: A 128x64 (8192 el) | B 128x64 (8192 el) = 32KB; 2 bufs = 64KB
  __shared__ __align__(16) ushort_t lds[2][16384];

  // 512 blocks = 64 bm x 8 bn. XCD swizzle: xcd = bid&7 owns 64 consecutive
  // logical ids -> 8 A-panels (2MB) + full B (2MB) resident per XCD L2.
  const int bid = blockIdx.x;
  const int logical = (bid & 7) * 64 + (bid >> 3);
  const int bm0 = (logical >> 3) * 128;
  const int bn0 = (logical & 7) * 128;

  const int tid = threadIdx.x;
  const int w = tid >> 6, l = tid & 63;
  const int wr = w >> 1, wc = w & 1;          // 2x2 waves -> 64x64 per wave

  // ---- staging (8 gloads/thread: 4 A + 4 B); wave w rows [w*32, w*32+32) ----
  const int srow = l >> 3;                    // 0..7 within 8-row chunk
  const int sclog = (l & 7) ^ srow;           // pre-swizzled source chunk
  const size_t gA0 = (size_t)(bm0 + w * 32 + srow) * K + sclog * 8;
  const size_t gB0 = (size_t)(bn0 + w * 32 + srow) * K + sclog * 8;
  const int ldsAo = w * 2048 + l * 8;         // elems
  const int ldsBo = 8192 + w * 2048 + l * 8;

#define STAGE(s, t1) do { \
    const ushort_t* ga = Ag + gA0 + (size_t)(t1) * 64; \
    const ushort_t* gb = Bg + gB0 + (size_t)(t1) * 64; \
    GLOAD16(ga,          &lds[s][ldsAo]); \
    GLOAD16(ga + 8 * K,  &lds[s][ldsAo + 512]); \
    GLOAD16(ga + 16 * K, &lds[s][ldsAo + 1024]); \
    GLOAD16(ga + 24 * K, &lds[s][ldsAo + 1536]); \
    GLOAD16(gb,          &lds[s][ldsBo]); \
    GLOAD16(gb + 8 * K,  &lds[s][ldsBo + 512]); \
    GLOAD16(gb + 16 * K, &lds[s][ldsBo + 1024]); \
    GLOAD16(gb + 24 * K, &lds[s][ldsBo + 1536]); } while (0)

  // ---- fragment read addressing (swizzled: phys chunk = logical ^ (row&7)) ----
  const int r = l & 15, kb = l >> 4, xr = r & 7;
  const int aRow = (wr * 64 + r) * 64;        // + m*1024 + chunk*8
  const int bRow = 8192 + (wc * 64 + r) * 64;
  const int c0 = ((0 | kb) ^ xr) * 8;
  const int c1 = ((4 | kb) ^ xr) * 8;

  f32x4 acc[4][4];
#pragma unroll
  for (int m = 0; m < 4; ++m)
#pragma unroll
    for (int n = 0; n < 4; ++n) acc[m][n] = (f32x4){0.f, 0.f, 0.f, 0.f};

  STAGE(0, 0);

  for (int t = 0; t < NT; ++t) {
    const int cur = t & 1;
    __builtin_amdgcn_s_barrier();           // all waves done reading buf cur^1
    if (t + 1 < NT) {
      STAGE(cur ^ 1, t + 1);
      asm volatile("s_waitcnt vmcnt(8)" ::: "memory");  // tile t done; t+1 in flight
    } else {
      asm volatile("s_waitcnt vmcnt(0)" ::: "memory");
    }
    __builtin_amdgcn_s_barrier();           // tile t resident for all waves
    __builtin_amdgcn_sched_barrier(0);

    const ushort_t* Lb = &lds[cur][0];
    bf16x8 av[4], bv[4];
    // ---- k-slice 0 ----
#pragma unroll
    for (int m = 0; m < 4; ++m) av[m] = *(const bf16x8*)(Lb + aRow + m * 1024 + c0);
#pragma unroll
    for (int n = 0; n < 4; ++n) bv[n] = *(const bf16x8*)(Lb + bRow + n * 1024 + c0);
    __builtin_amdgcn_s_setprio(1);
#pragma unroll
    for (int m = 0; m < 4; ++m)
#pragma unroll
      for (int n = 0; n < 4; ++n)
        acc[m][n] = __builtin_amdgcn_mfma_f32_16x16x32_bf16(av[m], bv[n], acc[m][n], 0, 0, 0);
    __builtin_amdgcn_s_setprio(0);
    // ---- k-slice 1 ----
#pragma unroll
    for (int m = 0; m < 4; ++m) av[m] = *(const bf16x8*)(Lb + aRow + m * 1024 + c1);
#pragma unroll
    for (int n = 0; n < 4; ++n) bv[n] = *(const bf16x8*)(Lb + bRow + n * 1024 + c1);
    __builtin_amdgcn_s_setprio(1);
#pragma unroll
    for (int m = 0; m < 4; ++m)
#pragma unroll
      for (int n = 0; n < 4; ++n)
        acc[m][n] = __builtin_amdgcn_mfma_f32_16x16x32_bf16(av[m], bv[n], acc[m][n], 0, 0, 0);
    __builtin_amdgcn_s_setprio(0);
  }
#undef STAGE

  // ---- epilogue: stage C (bf16) through LDS, 16B-coalesced global I/O ----
  // C overlay: 128 rows x 136 elems (272B row stride, 16B-aligned, low conflict)
  __syncthreads();
  ushort_t* C = &lds[0][0];
  const int er = (l >> 4) * 4;
  const int ec = l & 15;
#pragma unroll
  for (int n = 0; n < 4; ++n) {
    const int lc = wc * 64 + n * 16 + ec;
    const float bvx = bias[bn0 + lc];
    const float add = (MODE == 1) ? (bvx + tval * wlast[bn0 + lc]) : bvx;
#pragma unroll
    for (int m = 0; m < 4; ++m) {
#pragma unroll
      for (int j = 0; j < 4; ++j) {
        const int lr = wr * 64 + m * 16 + er + j;
        const float v = acc[m][n][j] + add;
        C[lr * 136 + lc] = (MODE == 3) ? f2bf(v) : f2bf(fast_tanh(v));
      }
    }
  }
  __syncthreads();

#pragma unroll
  for (int i = 0; i < 8; ++i) {
    const int chunk = tid + i * 256;        // 2048 chunks of 8 elems
    const int row = chunk >> 4;
    const int cc = chunk & 15;
    const us8 kv8 = *(const us8*)&C[row * 136 + cc * 8];
    const size_t gidx = (size_t)(bm0 + row) * NCOL + bn0 + cc * 8;
    if (MODE != 3) {
      *(us8*)&Xout[gidx] = kv8;
    } else if (S == 0) {
      *(us8*)&ksum[gidx] = kv8;
      const us8 hb8 = *(const us8*)&hbr[gidx];
      us8 o;
#pragma unroll
      for (int e = 0; e < 8; ++e) o[e] = f2bf(b2f(hb8[e]) + (DT * 0.5f) * b2f(kv8[e]));
      *(us8*)&Xout[gidx] = o;
    } else if (S == 1 || S == 2) {
      const us8 ks8 = *(const us8*)&ksum[gidx];
      const us8 hb8 = *(const us8*)&hbr[gidx];
      us8 nks, o;
      const float c = (S == 1) ? (DT * 0.5f) : DT;
#pragma unroll
      for (int e = 0; e < 8; ++e) {
        const float kv = b2f(kv8[e]);
        nks[e] = f2bf(b2f(ks8[e]) + 2.f * kv);
        o[e] = f2bf(b2f(hb8[e]) + c * kv);
      }
      *(us8*)&ksum[gidx] = nks;
      *(us8*)&Xout[gidx] = o;
    } else {
      const us8 ks8 = *(const us8*)&ksum[gidx];
      const f32x8 h8 = *(const f32x8*)&h0[gidx];
      f32x8 hn; us8 o;
#pragma unroll
      for (int e = 0; e < 8; ++e) {
        hn[e] = h8[e] + (DT / 6.f) * (b2f(ks8[e]) + b2f(kv8[e]));
        o[e] = f2bf(hn[e]);
      }
      *(f32x8*)&h1[gidx] = hn;
      *(us8*)&Xout[gidx] = o;
    }
  }
}

extern "C" void kernel_launch(void* const* d_in, const int* in_sizes, int n_in,
                              void* d_out, int out_size, void* d_ws, size_t ws_size,
                              hipStream_t stream) {
  (void)in_sizes; (void)n_in; (void)out_size; (void)ws_size;
  const float* h_in = (const float*)d_in[0];
  const float* W1   = (const float*)d_in[1];   // 1025 x 1024
  const float* b1   = (const float*)d_in[2];
  const float* W2   = (const float*)d_in[3];
  const float* b2   = (const float*)d_in[4];
  const float* W3   = (const float*)d_in[5];
  const float* b3   = (const float*)d_in[6];

  char* ws = (char*)d_ws;
  ushort_t* W1t  = (ushort_t*)(ws);                        // 2 MiB
  ushort_t* W2t  = (ushort_t*)(ws + (2ull << 20));         // 2 MiB
  ushort_t* W3t  = (ushort_t*)(ws + (4ull << 20));         // 2 MiB
  ushort_t* hb   = (ushort_t*)(ws + (6ull << 20));         // 16 MiB bf16 h
  ushort_t* X1   = (ushort_t*)(ws + (22ull << 20));        // 16 MiB
  ushort_t* X2   = (ushort_t*)(ws + (38ull << 20));        // 16 MiB
  ushort_t* Xs   = (ushort_t*)(ws + (54ull << 20));        // 16 MiB stage input
  ushort_t* KS   = (ushort_t*)(ws + (70ull << 20));        // 16 MiB bf16 ksum
  float*    OUT  = (float*)d_out;                          // fp32 h (in-place)

  dim3 tb(32, 8);
  dim3 tg(32, 32);
  transpose_bf16<<<tg, tb, 0, stream>>>(W1, W1t);
  transpose_bf16<<<tg, tb, 0, stream>>>(W2, W2t);
  transpose_bf16<<<tg, tb, 0, stream>>>(W3, W3t);
  conv_bf16<<<8192, 256, 0, stream>>>(h_in, hb);

  const float dt = 0.1f;
  const float* W1last = W1 + (size_t)1024 * 1024;
  constexpr int GRID = 512, BLK = 256;

  for (int step = 0; step < 10; ++step) {
    const float t0 = step * dt;
    const float* h0p = (step == 0) ? h_in : (const float*)OUT;

    // stage 0 (t = t0), A = hb
    gemm_fused<1, 0><<<GRID, BLK, 0, stream>>>(hb, W1t, b1, W1last, t0, X1, nullptr, nullptr, nullptr, nullptr);
    gemm_fused<2, 0><<<GRID, BLK, 0, stream>>>(X1, W2t, b2, nullptr, 0.f, X2, nullptr, nullptr, nullptr, nullptr);
    gemm_fused<3, 0><<<GRID, BLK, 0, stream>>>(X2, W3t, b3, nullptr, 0.f, Xs, KS, hb, nullptr, nullptr);

    // stage 1 (t = t0 + dt/2), A = Xs
    gemm_fused<1, 0><<<GRID, BLK, 0, stream>>>(Xs, W1t, b1, W1last, t0 + 0.5f * dt, X1, nullptr, nullptr, nullptr, nullptr);
    gemm_fused<2, 0><<<GRID, BLK, 0, stream>>>(X1, W2t, b2, nullptr, 0.f, X2, nullptr, nullptr, nullptr, nullptr);
    gemm_fused<3, 1><<<GRID, BLK, 0, stream>>>(X2, W3t, b3, nullptr, 0.f, Xs, KS, hb, nullptr, nullptr);

    // stage 2 (t = t0 + dt/2)
    gemm_fused<1, 0><<<GRID, BLK, 0, stream>>>(Xs, W1t, b1, W1last, t0 + 0.5f * dt, X1, nullptr, nullptr, nullptr, nullptr);
    gemm_fused<2, 0><<<GRID, BLK, 0, stream>>>(X1, W2t, b2, nullptr, 0.f, X2, nullptr, nullptr, nullptr, nullptr);
    gemm_fused<3, 2><<<GRID, BLK, 0, stream>>>(X2, W3t, b3, nullptr, 0.f, Xs, KS, hb, nullptr, nullptr);

    // stage 3 (t = t0 + dt); S3 writes h1 (in-place OUT) + hb
    gemm_fused<1, 0><<<GRID, BLK, 0, stream>>>(Xs, W1t, b1, W1last, t0 + dt, X1, nullptr, nullptr, nullptr, nullptr);
    gemm_fused<2, 0><<<GRID, BLK, 0, stream>>>(X1, W2t, b2, nullptr, 0.f, X2, nullptr, nullptr, nullptr, nullptr);
    gemm_fused<3, 3><<<GRID, BLK, 0, stream>>>(X2, W3t, b3, nullptr, 0.f, hb, KS, nullptr, h0p, OUT);
  }
}